// Round 4
// baseline (1012.841 us; speedup 1.0000x reference)
//
#include <hip/hip_runtime.h>
#include <stdint.h>

// HT model: exact 3-way bf16 split (x = h+m+l, 3x8=24 mantissa bits) + MFMA.
// 8 of 9 cross products (drop l*l <= 2^-32) on v_mfma_f32_32x32x16_bf16,
// single fp32 accumulator (noise class == round-1 fp32 chain, measured OK).
//
// Weights pre-split AND pre-swizzled into MFMA A-operand fragment order in
// global memory; staged to LDS via global_load_lds (width 16, no VALU, no
// ds_write). Activations split in-kernel during staging, written in
// fragment-linear LDS order -> all ds_read_b128 are lane-contiguous
// (conflict-free). Wave tile up to 128x128 (4x4 tiles of 32x32) for LDS/MFMA
// balance. All intermediates fp32, b-major [node][b][k]. Needs ws >= 185 MB.

typedef short short8 __attribute__((ext_vector_type(8)));
typedef float floatx16 __attribute__((ext_vector_type(16)));

__device__ __forceinline__ unsigned bf16_rne(float x) {
    unsigned u = __float_as_uint(x);
    return (u + 0x7FFFu + ((u >> 16) & 1u)) >> 16;
}
__device__ __forceinline__ float bf16_f(unsigned h) { return __uint_as_float(h << 16); }
__device__ __forceinline__ void split3(float x, unsigned& h, unsigned& m, unsigned& l) {
    h = bf16_rne(x);
    float r1 = x - bf16_f(h);      // exact (Sterbenz)
    m = bf16_rne(r1);
    float r2 = r1 - bf16_f(m);     // exact
    l = bf16_rne(r2);
}

// ---------------- weight pre-split into fragment-ordered bf16 planes ----------------
// Plane layout per level: frag = ((z*3+p)*(K/16) + kc)*NGTtot + (g>>5), 512 shorts
// per frag; within frag: slot = (g&31) | ((k>>3 & 1)<<5), 8 shorts (16B) per slot.
struct Seg { const float* src; long dst; int Z, G, Gpad, K, trans, blk0; };
struct SegTable { Seg s[11]; };

__global__ __launch_bounds__(256) void presplit(SegTable T, unsigned short* P) {
    int blk = blockIdx.x;
    int si = 0;
#pragma unroll
    for (int i = 1; i < 11; ++i) if (blk >= T.s[i].blk0) si = i;
    Seg d = T.s[si];
    const int K8 = d.K >> 3;
    long total = (long)d.Z * d.Gpad * K8;
    long o = (long)(blk - d.blk0) * 256 + threadIdx.x;
    if (o >= total) return;
    int k8 = (int)(o % K8);
    long rem = o / K8;
    int g = (int)(rem % d.Gpad);
    int z = (int)(rem / d.Gpad);
    float e[8];
    if (g < d.G) {
        if (!d.trans) {
            const float* s = d.src + ((long)z * d.G + g) * d.K + k8 * 8;
            float4 a = *(const float4*)s, b = *(const float4*)(s + 4);
            e[0]=a.x; e[1]=a.y; e[2]=a.z; e[3]=a.w; e[4]=b.x; e[5]=b.y; e[6]=b.z; e[7]=b.w;
        } else {
#pragma unroll
            for (int i = 0; i < 8; ++i) e[i] = d.src[(long)(k8 * 8 + i) * d.G + g];
        }
    } else {
#pragma unroll
        for (int i = 0; i < 8; ++i) e[i] = 0.f;
    }
    unsigned h[8], m[8], l[8];
#pragma unroll
    for (int i = 0; i < 8; ++i) split3(e[i], h[i], m[i], l[i]);
    uint4 Pp[3];
    Pp[0] = { h[0]|(h[1]<<16), h[2]|(h[3]<<16), h[4]|(h[5]<<16), h[6]|(h[7]<<16) };
    Pp[1] = { m[0]|(m[1]<<16), m[2]|(m[3]<<16), m[4]|(m[5]<<16), m[6]|(m[7]<<16) };
    Pp[2] = { l[0]|(l[1]<<16), l[2]|(l[3]<<16), l[4]|(l[5]<<16), l[6]|(l[7]<<16) };
    const int NGTt = d.Gpad >> 5;
    const int KC16 = d.K >> 4;
    const long slot = (long)((g & 31) | ((k8 & 1) << 5)) * 8;
#pragma unroll
    for (int p = 0; p < 3; ++p) {
        long frag = ((long)(z * 3 + p) * KC16 + (k8 >> 1)) * NGTt + (g >> 5);
        *(uint4*)&P[d.dst + frag * 512 + slot] = Pp[p];
    }
}

// ---------------- main GEMM: C[z][b][g] = sum_k W[z][g][k] * Act[z][b][k] ----------------
template<int GTW, int WAVB, int MINW>
__global__ __launch_bounds__(256, MINW) void ht_mfma(
    const float* __restrict__ Act,
    const unsigned short* __restrict__ Wp,   // level plane base (frag-ordered)
    const float* __restrict__ bias,
    float* __restrict__ C,
    int K, int Gtot, int NGTtot,
    long act_z, long act_pair, int act_rb,
    long c_z, int c_rb, int relu)
{
    constexpr int WAVG = 4 / WAVB;
    constexpr int BB   = WAVB * 128;            // block b-size
    constexpr int GG   = WAVG * GTW * 32;       // block g-size
    constexpr int NBT  = BB / 32;
    constexpr int NGT  = GG / 32;

    __shared__ unsigned short AS[3 * NBT * 1024];
    __shared__ unsigned short WS[3 * NGT * 1024];

    const int tid  = threadIdx.x;
    const int lane = tid & 63;
    const int w    = tid >> 6;
    const int bw   = w % WAVB;
    const int gw   = w / WAVB;

    const int b0 = blockIdx.x * BB;
    const int g0 = blockIdx.y * GG;
    const int z  = blockIdx.z;

    const float* Abase = Act + (long)z * act_z + (long)b0 * act_rb;

    // per-lane constant LDS granule offsets (in shorts)
    const int aslot = ((lane & 31) * 2 + (lane >> 5)) * 8;
    const int wslot = lane * 8;
    const int KC16  = K >> 4;

    floatx16 acc[4][GTW];
#pragma unroll
    for (int bt = 0; bt < 4; ++bt)
#pragma unroll
        for (int gt = 0; gt < GTW; ++gt) acc[bt][gt] = (floatx16)0.f;

    for (int k0 = 0; k0 < K; k0 += 32) {
        // ---- stage activations: fp32 load (+pair product) -> split -> 3 planes
#pragma unroll
        for (int r = 0; r < BB / 64; ++r) {
            const int s   = r * 256 + tid;
            const int b   = s >> 2;
            const int oct = s & 3;
            const float* p = Abase + (long)b * act_rb + k0 + oct * 8;
            float4 v0 = *(const float4*)p;
            float4 v1 = *(const float4*)(p + 4);
            if (act_pair) {
                float4 u0 = *(const float4*)(p + act_pair);
                float4 u1 = *(const float4*)(p + act_pair + 4);
                v0.x *= u0.x; v0.y *= u0.y; v0.z *= u0.z; v0.w *= u0.w;
                v1.x *= u1.x; v1.y *= u1.y; v1.z *= u1.z; v1.w *= u1.w;
            }
            float e[8] = { v0.x, v0.y, v0.z, v0.w, v1.x, v1.y, v1.z, v1.w };
            unsigned h[8], m[8], l[8];
#pragma unroll
            for (int i = 0; i < 8; ++i) split3(e[i], h[i], m[i], l[i]);
            uint4 Ph = { h[0]|(h[1]<<16), h[2]|(h[3]<<16), h[4]|(h[5]<<16), h[6]|(h[7]<<16) };
            uint4 Pm = { m[0]|(m[1]<<16), m[2]|(m[3]<<16), m[4]|(m[5]<<16), m[6]|(m[7]<<16) };
            uint4 Pl = { l[0]|(l[1]<<16), l[2]|(l[3]<<16), l[4]|(l[5]<<16), l[6]|(l[7]<<16) };
            const int base = (b >> 5) * 1024 + (oct >> 1) * 512 + ((b & 31) * 2 + (oct & 1)) * 8;
            *(uint4*)&AS[base] = Ph;
            *(uint4*)&AS[NBT * 1024 + base] = Pm;
            *(uint4*)&AS[2 * NBT * 1024 + base] = Pl;
        }
        // ---- stage weights via async DMA (pre-split, frag-ordered)
        {
            const int NF = 3 * NGT * 2;
            for (int f = w; f < NF; f += 4) {
                const int p  = f / (NGT * 2);
                const int gt = (f >> 1) % NGT;
                const int kc = f & 1;
                const long frag = ((long)(z * 3 + p) * KC16 + (k0 >> 4) + kc) * NGTtot
                                  + (g0 >> 5) + gt;
                const unsigned short* gp = Wp + frag * 512 + wslot;
                unsigned short* lp = &WS[((p * NGT + gt) * 2 + kc) * 512];
                __builtin_amdgcn_global_load_lds(
                    (const __attribute__((address_space(1))) unsigned int*)gp,
                    (__attribute__((address_space(3))) unsigned int*)lp,
                    16, 0, 0);
            }
        }
        __syncthreads();
        // ---- compute: 8 split-products on 32x32x16 MFMA
#pragma unroll
        for (int kc = 0; kc < 2; ++kc) {
            short8 af[3][4];
#pragma unroll
            for (int sb = 0; sb < 3; ++sb)
#pragma unroll
                for (int bt = 0; bt < 4; ++bt)
                    af[sb][bt] = *(const short8*)&AS[(sb * NBT + bw * 4 + bt) * 1024
                                                     + kc * 512 + aslot];
#pragma unroll
            for (int sa = 0; sa < 3; ++sa) {
#pragma unroll
                for (int gt = 0; gt < GTW; ++gt) {
                    short8 wf = *(const short8*)&WS[(sa * NGT + gw * GTW + gt) * 1024
                                                    + kc * 512 + wslot];
                    const int nsb = (sa == 2) ? 2 : 3;
#pragma unroll
                    for (int sb = 0; sb < 3; ++sb) {
                        if (sb >= nsb) continue;
#pragma unroll
                        for (int bt = 0; bt < 4; ++bt)
                            acc[bt][gt] = __builtin_amdgcn_mfma_f32_32x32x16_bf16(
                                wf, af[sb][bt], acc[bt][gt], 0, 0, 0);
                    }
                }
            }
        }
        __syncthreads();
    }
    // ---- epilogue: D col=lane&31 (b), row=(reg&3)+8*(reg>>2)+4*(lane>>5) (g)
    const int koct = lane >> 5;
#pragma unroll
    for (int bt = 0; bt < 4; ++bt) {
        const int b = b0 + bw * 128 + bt * 32 + (lane & 31);
        float* crow = C + (long)z * c_z + (long)b * c_rb;
#pragma unroll
        for (int gt = 0; gt < GTW; ++gt) {
            const int gb = g0 + gw * (GTW * 32) + gt * 32 + 4 * koct;
#pragma unroll
            for (int r4 = 0; r4 < 4; ++r4) {
                const int g = gb + r4 * 8;
                float4 o;
                o.x = acc[bt][gt][r4 * 4 + 0];
                o.y = acc[bt][gt][r4 * 4 + 1];
                o.z = acc[bt][gt][r4 * 4 + 2];
                o.w = acc[bt][gt][r4 * 4 + 3];
                if (bias) {
                    float4 bv = *(const float4*)(bias + g);
                    o.x += bv.x; o.y += bv.y; o.z += bv.z; o.w += bv.w;
                }
                if (relu) {
                    o.x = fmaxf(o.x, 0.f); o.y = fmaxf(o.y, 0.f);
                    o.z = fmaxf(o.z, 0.f); o.w = fmaxf(o.w, 0.f);
                }
                if (g + 3 < Gtot) {
                    *(float4*)(crow + g) = o;
                } else if (g < Gtot) {
                    crow[g] = o.x;
                    if (g + 1 < Gtot) crow[g + 1] = o.y;
                    if (g + 2 < Gtot) crow[g + 2] = o.z;
                }
            }
        }
    }
}

extern "C" void kernel_launch(void* const* d_in, const int* in_sizes, int n_in,
                              void* d_out, int out_size, void* d_ws, size_t ws_size,
                              hipStream_t stream)
{
    const float* X    = (const float*)d_in[0];
    const float* W1   = (const float*)d_in[1];
    const float* b1   = (const float*)d_in[2];
    const float* W2   = (const float*)d_in[3];
    const float* b2   = (const float*)d_in[4];
    const float* W3   = (const float*)d_in[5];
    const float* b3   = (const float*)d_in[6];
    const float* W4   = (const float*)d_in[7];
    const float* b4   = (const float*)d_in[8];
    const float* P0   = (const float*)d_in[9];
    const float* P1   = (const float*)d_in[10];
    const float* P2   = (const float*)d_in[11];
    const float* P3   = (const float*)d_in[12];
    const float* P4   = (const float*)d_in[13];
    const float* P5   = (const float*)d_in[14];
    const float* Ptop = (const float*)d_in[15];
    float* out = (float*)d_out;

    unsigned short* planes = (unsigned short*)d_ws;
    float* base = (float*)d_ws;
    // planes: [0, 12248064) shorts = [0, 6124032) floats; float region from 6291456
    float* h1c = base + 6291456L;          // [131072][128]
    float* h2c = base + 23068672L;         // [131072][64]
    float* h3c = base + 6291456L;          // [131072][32] (h1c dead)
    float* Fc  = base + 10485760L;         // [131072][32]
    float* t0  = base + 31457280L;         // [64][4096][64]
    float* t1  = base + 6291456L;          // [32][4096][128]
    float* t2  = base + 23068672L;         // [16][4096][256]
    float* t3  = base + 6291456L;          // [8][4096][512]
    float* t4  = base + 39845888L;         // [4][4096][512]
    float* t5  = base + 23068672L;         // [2][4096][512]

    // ---- pre-split weights (frag-ordered planes)
    SegTable T;
    auto seg = [](const float* s, long dst, int Z, int G, int Gpad, int K, int tr, int b0) {
        Seg d; d.src=s; d.dst=dst; d.Z=Z; d.G=G; d.Gpad=Gpad; d.K=K; d.trans=tr; d.blk0=b0; return d;
    };
    T.s[0]  = seg(W1,   0L,        1, 128, 128,  64, 1, 0);
    T.s[1]  = seg(W2,   24576L,    1,  64,  64, 128, 1, 4);
    T.s[2]  = seg(W3,   49152L,    1,  32,  32,  64, 1, 8);
    T.s[3]  = seg(W4,   55296L,    1,  32,  32,  32, 1, 9);
    T.s[4]  = seg(P0,   58368L,   64,  64,  64,  32, 0, 10);
    T.s[5]  = seg(P1,   451584L,  32, 128, 128,  64, 0, 74);
    T.s[6]  = seg(P2,   1238016L, 16, 256, 256, 128, 0, 202);
    T.s[7]  = seg(P3,   2810880L,  8, 512, 512, 256, 0, 458);
    T.s[8]  = seg(P4,   5956608L,  4, 512, 512, 512, 0, 970);
    T.s[9]  = seg(P5,   9102336L,  2, 512, 512, 512, 0, 1482);
    T.s[10] = seg(Ptop, 10675200L, 1, 1000, 1024, 512, 0, 1738);
    presplit<<<dim3(1994), dim3(256), 0, stream>>>(T, planes);

    dim3 blk(256, 1, 1);

    // ---- MLP + leaf, 2 chunks of 131072 tokens
    for (int c = 0; c < 2; ++c) {
        const float* Xc = X + (long)c * 131072 * 64;
        // mlp1: 64->128 relu    (block 256b x 128g, 2 blocks/CU)
        ht_mfma<2, 2, 2><<<dim3(512, 1, 1), blk, 0, stream>>>(
            Xc, planes + 0, b1, h1c, 64, 128, 4, 0L, 0L, 64, 0L, 128, 1);
        // mlp2: 128->64 relu    (block 512b x 64g)
        ht_mfma<2, 4, 1><<<dim3(256, 1, 1), blk, 0, stream>>>(
            h1c, planes + 24576, b2, h2c, 128, 64, 2, 0L, 0L, 128, 0L, 64, 1);
        // mlp3: 64->32 relu     (block 512b x 32g)
        ht_mfma<1, 4, 1><<<dim3(256, 1, 1), blk, 0, stream>>>(
            h2c, planes + 49152, b3, h3c, 64, 32, 1, 0L, 0L, 64, 0L, 32, 1);
        // mlp4: 32->32
        ht_mfma<1, 4, 1><<<dim3(256, 1, 1), blk, 0, stream>>>(
            h3c, planes + 55296, b4, Fc, 32, 32, 1, 0L, 0L, 32, 0L, 32, 0);
        // leaf: t0[j][b][a] = sum_m P0[j][a][m] * F[(b,j)][m]
        ht_mfma<2, 4, 1><<<dim3(4, 1, 64), blk, 0, stream>>>(
            Fc, planes + 58368, nullptr, t0 + (long)c * 131072, 32, 64, 2,
            32L, 0L, 2048, 262144L, 64, 0);
    }

    // ---- tree: t_l[n][b][g] = sum_a P_l[n][g][a] * t[2n][b][a]*t[2n+1][b][a]
    ht_mfma<2, 2, 2><<<dim3(16, 1, 32), blk, 0, stream>>>(   // L1 K=64 G=128
        t0, planes + 451584, nullptr, t1, 64, 128, 4,
        524288L, 262144L, 64, 524288L, 128, 0);
    ht_mfma<4, 2, 1><<<dim3(16, 1, 16), blk, 0, stream>>>(   // L2 K=128 G=256
        t1, planes + 1238016, nullptr, t2, 128, 256, 8,
        1048576L, 524288L, 128, 1048576L, 256, 0);
    ht_mfma<4, 2, 1><<<dim3(16, 2, 8), blk, 0, stream>>>(    // L3 K=256 G=512
        t2, planes + 2810880, nullptr, t3, 256, 512, 16,
        2097152L, 1048576L, 256, 2097152L, 512, 0);
    ht_mfma<4, 2, 1><<<dim3(16, 2, 4), blk, 0, stream>>>(    // L4 K=512 G=512
        t3, planes + 5956608, nullptr, t4, 512, 512, 16,
        4194304L, 2097152L, 512, 2097152L, 512, 0);
    ht_mfma<4, 2, 1><<<dim3(16, 2, 2), blk, 0, stream>>>(    // L5 K=512 G=512
        t4, planes + 9102336, nullptr, t5, 512, 512, 16,
        4194304L, 2097152L, 512, 2097152L, 512, 0);
    ht_mfma<4, 2, 1><<<dim3(16, 4, 1), blk, 0, stream>>>(    // top K=512 G=1000 (pad 1024)
        t5, planes + 10675200, nullptr, out, 512, 1000, 32,
        0L, 2097152L, 512, 0L, 1000, 0);
}

// Round 5
// 653.854 us; speedup vs baseline: 1.5490x; 1.5490x over previous
//
#include <hip/hip_runtime.h>
#include <stdint.h>

// HT model: exact 3-way bf16 split (x = h+m+l, 3x8=24 mantissa bits) + MFMA.
// 8 of 9 cross products (drop l*l <= 2^-32) on v_mfma_f32_32x32x16_bf16,
// single fp32 accumulator (verified: absmax identical to fp32-VALU chain).
//
// r5 geometry: wave tile 64b x (GTW*32)g (bt=2), block <=128x128, LDS <=54 KB,
// launch_bounds(256,3) -> 3 blocks/CU, 12 waves/CU (r4's 1-block/CU latency
// cliff removed). Weights pre-split+pre-swizzled to MFMA fragment order,
// staged via global_load_lds (no ds_write, conflict-free). Activations split
// in-kernel. All intermediates fp32, b-major [node][b][k]. ws >= 185 MB.

typedef short short8 __attribute__((ext_vector_type(8)));
typedef float floatx16 __attribute__((ext_vector_type(16)));

__device__ __forceinline__ unsigned bf16_rne(float x) {
    unsigned u = __float_as_uint(x);
    return (u + 0x7FFFu + ((u >> 16) & 1u)) >> 16;
}
__device__ __forceinline__ float bf16_f(unsigned h) { return __uint_as_float(h << 16); }
__device__ __forceinline__ void split3(float x, unsigned& h, unsigned& m, unsigned& l) {
    h = bf16_rne(x);
    float r1 = x - bf16_f(h);      // exact (Sterbenz)
    m = bf16_rne(r1);
    float r2 = r1 - bf16_f(m);     // exact
    l = bf16_rne(r2);
}

// ---------------- weight pre-split into fragment-ordered bf16 planes ----------------
// frag = ((z*3+p)*(K/16) + kc)*NGTtot + (g>>5), 512 shorts per frag;
// slot within frag = ((g&31) | ((k8&1)<<5)) * 8 shorts (16B granule).
struct Seg { const float* src; long dst; int Z, G, Gpad, K, trans, blk0; };
struct SegTable { Seg s[11]; };

__global__ __launch_bounds__(256) void presplit(SegTable T, unsigned short* P) {
    int blk = blockIdx.x;
    int si = 0;
#pragma unroll
    for (int i = 1; i < 11; ++i) if (blk >= T.s[i].blk0) si = i;
    Seg d = T.s[si];
    const int K8 = d.K >> 3;
    long total = (long)d.Z * d.Gpad * K8;
    long o = (long)(blk - d.blk0) * 256 + threadIdx.x;
    if (o >= total) return;
    int k8 = (int)(o % K8);
    long rem = o / K8;
    int g = (int)(rem % d.Gpad);
    int z = (int)(rem / d.Gpad);
    float e[8];
    if (g < d.G) {
        if (!d.trans) {
            const float* s = d.src + ((long)z * d.G + g) * d.K + k8 * 8;
            float4 a = *(const float4*)s, b = *(const float4*)(s + 4);
            e[0]=a.x; e[1]=a.y; e[2]=a.z; e[3]=a.w; e[4]=b.x; e[5]=b.y; e[6]=b.z; e[7]=b.w;
        } else {
#pragma unroll
            for (int i = 0; i < 8; ++i) e[i] = d.src[(long)(k8 * 8 + i) * d.G + g];
        }
    } else {
#pragma unroll
        for (int i = 0; i < 8; ++i) e[i] = 0.f;
    }
    unsigned h[8], m[8], l[8];
#pragma unroll
    for (int i = 0; i < 8; ++i) split3(e[i], h[i], m[i], l[i]);
    uint4 Pp[3];
    Pp[0] = { h[0]|(h[1]<<16), h[2]|(h[3]<<16), h[4]|(h[5]<<16), h[6]|(h[7]<<16) };
    Pp[1] = { m[0]|(m[1]<<16), m[2]|(m[3]<<16), m[4]|(m[5]<<16), m[6]|(m[7]<<16) };
    Pp[2] = { l[0]|(l[1]<<16), l[2]|(l[3]<<16), l[4]|(l[5]<<16), l[6]|(l[7]<<16) };
    const int NGTt = d.Gpad >> 5;
    const int KC16 = d.K >> 4;
    const long slot = (long)((g & 31) | ((k8 & 1) << 5)) * 8;
#pragma unroll
    for (int p = 0; p < 3; ++p) {
        long frag = ((long)(z * 3 + p) * KC16 + (k8 >> 1)) * NGTt + (g >> 5);
        *(uint4*)&P[d.dst + frag * 512 + slot] = Pp[p];
    }
}

// ---------------- main GEMM: C[z][b][g] = sum_k W[z][g][k] * Act[z][b][k] ----------------
// Wave grid: BWAVES=4/GWAVES along b, GWAVES along g. Wave tile 64b x GTW*32 g.
template<int GTW, int GWAVES>
__global__ __launch_bounds__(256, 3) void ht_mfma(
    const float* __restrict__ Act,
    const unsigned short* __restrict__ Wp,   // level plane base (frag-ordered)
    const float* __restrict__ bias,
    float* __restrict__ C,
    int K, int Gtot, int NGTtot,
    long act_z, long act_pair, int act_rb,
    long c_z, int c_rb, int relu)
{
    constexpr int BWAVES = 4 / GWAVES;
    constexpr int BB  = BWAVES * 64;
    constexpr int GG  = GWAVES * GTW * 32;
    constexpr int NBT = BB / 32;
    constexpr int NGT = GG / 32;

    __shared__ unsigned short AS[3 * NBT * 1024];
    __shared__ unsigned short WS[3 * NGT * 1024];

    const int tid  = threadIdx.x;
    const int lane = tid & 63;
    const int w    = tid >> 6;
    const int bw   = w % BWAVES;
    const int gw   = w / BWAVES;

    const int b0 = blockIdx.x * BB;
    const int g0 = blockIdx.y * GG;
    const int z  = blockIdx.z;

    const float* Abase = Act + (long)z * act_z + (long)b0 * act_rb;

    const int aslot = ((lane & 31) * 2 + (lane >> 5)) * 8;
    const int wslot = lane * 8;
    const int KC16  = K >> 4;

    floatx16 acc[2][GTW];
#pragma unroll
    for (int bt = 0; bt < 2; ++bt)
#pragma unroll
        for (int gt = 0; gt < GTW; ++gt) acc[bt][gt] = (floatx16)0.f;

    for (int k0 = 0; k0 < K; k0 += 32) {
        // ---- stage activations: fp32 load (+pair product) -> split -> 3 planes
#pragma unroll
        for (int r = 0; r < BB / 64; ++r) {
            const int s   = r * 256 + tid;
            const int b   = s >> 2;
            const int oct = s & 3;
            const float* p = Abase + (long)b * act_rb + k0 + oct * 8;
            float4 v0 = *(const float4*)p;
            float4 v1 = *(const float4*)(p + 4);
            if (act_pair) {
                float4 u0 = *(const float4*)(p + act_pair);
                float4 u1 = *(const float4*)(p + act_pair + 4);
                v0.x *= u0.x; v0.y *= u0.y; v0.z *= u0.z; v0.w *= u0.w;
                v1.x *= u1.x; v1.y *= u1.y; v1.z *= u1.z; v1.w *= u1.w;
            }
            float e[8] = { v0.x, v0.y, v0.z, v0.w, v1.x, v1.y, v1.z, v1.w };
            unsigned h[8], m[8], l[8];
#pragma unroll
            for (int i = 0; i < 8; ++i) split3(e[i], h[i], m[i], l[i]);
            uint4 Ph = { h[0]|(h[1]<<16), h[2]|(h[3]<<16), h[4]|(h[5]<<16), h[6]|(h[7]<<16) };
            uint4 Pm = { m[0]|(m[1]<<16), m[2]|(m[3]<<16), m[4]|(m[5]<<16), m[6]|(m[7]<<16) };
            uint4 Pl = { l[0]|(l[1]<<16), l[2]|(l[3]<<16), l[4]|(l[5]<<16), l[6]|(l[7]<<16) };
            const int base = (b >> 5) * 1024 + (oct >> 1) * 512 + ((b & 31) * 2 + (oct & 1)) * 8;
            *(uint4*)&AS[base] = Ph;
            *(uint4*)&AS[NBT * 1024 + base] = Pm;
            *(uint4*)&AS[2 * NBT * 1024 + base] = Pl;
        }
        // ---- stage weights via async DMA (pre-split, frag-ordered)
        {
            const int NF = 3 * NGT * 2;
            for (int f = w; f < NF; f += 4) {
                const int p  = f / (NGT * 2);
                const int gt = (f >> 1) % NGT;
                const int kc = f & 1;
                const long frag = ((long)(z * 3 + p) * KC16 + (k0 >> 4) + kc) * NGTtot
                                  + (g0 >> 5) + gt;
                const unsigned short* gp = Wp + frag * 512 + wslot;
                unsigned short* lp = &WS[((p * NGT + gt) * 2 + kc) * 512];
                __builtin_amdgcn_global_load_lds(
                    (const __attribute__((address_space(1))) unsigned int*)gp,
                    (__attribute__((address_space(3))) unsigned int*)lp,
                    16, 0, 0);
            }
        }
        __syncthreads();
        // ---- compute: 8 split-products on 32x32x16 MFMA
#pragma unroll
        for (int kc = 0; kc < 2; ++kc) {
            short8 af[3][2];
#pragma unroll
            for (int sb = 0; sb < 3; ++sb)
#pragma unroll
                for (int bt = 0; bt < 2; ++bt)
                    af[sb][bt] = *(const short8*)&AS[(sb * NBT + bw * 2 + bt) * 1024
                                                     + kc * 512 + aslot];
#pragma unroll
            for (int sa = 0; sa < 3; ++sa) {
#pragma unroll
                for (int gt = 0; gt < GTW; ++gt) {
                    short8 wf = *(const short8*)&WS[(sa * NGT + gw * GTW + gt) * 1024
                                                    + kc * 512 + wslot];
                    const int nsb = (sa == 2) ? 2 : 3;
#pragma unroll
                    for (int sb = 0; sb < 3; ++sb) {
                        if (sb >= nsb) continue;
#pragma unroll
                        for (int bt = 0; bt < 2; ++bt)
                            acc[bt][gt] = __builtin_amdgcn_mfma_f32_32x32x16_bf16(
                                wf, af[sb][bt], acc[bt][gt], 0, 0, 0);
                    }
                }
            }
        }
        __syncthreads();
    }
    // ---- epilogue: D col=lane&31 (b), row=(reg&3)+8*(reg>>2)+4*(lane>>5) (g)
    const int koct = lane >> 5;
#pragma unroll
    for (int bt = 0; bt < 2; ++bt) {
        const int b = b0 + bw * 64 + bt * 32 + (lane & 31);
        float* crow = C + (long)z * c_z + (long)b * c_rb;
#pragma unroll
        for (int gt = 0; gt < GTW; ++gt) {
            const int gb = g0 + gw * (GTW * 32) + gt * 32 + 4 * koct;
#pragma unroll
            for (int r4 = 0; r4 < 4; ++r4) {
                const int g = gb + r4 * 8;
                float4 o;
                o.x = acc[bt][gt][r4 * 4 + 0];
                o.y = acc[bt][gt][r4 * 4 + 1];
                o.z = acc[bt][gt][r4 * 4 + 2];
                o.w = acc[bt][gt][r4 * 4 + 3];
                if (bias) {
                    float4 bv = *(const float4*)(bias + g);
                    o.x += bv.x; o.y += bv.y; o.z += bv.z; o.w += bv.w;
                }
                if (relu) {
                    o.x = fmaxf(o.x, 0.f); o.y = fmaxf(o.y, 0.f);
                    o.z = fmaxf(o.z, 0.f); o.w = fmaxf(o.w, 0.f);
                }
                if (g + 3 < Gtot) {
                    *(float4*)(crow + g) = o;
                } else if (g < Gtot) {
                    crow[g] = o.x;
                    if (g + 1 < Gtot) crow[g + 1] = o.y;
                    if (g + 2 < Gtot) crow[g + 2] = o.z;
                }
            }
        }
    }
}

extern "C" void kernel_launch(void* const* d_in, const int* in_sizes, int n_in,
                              void* d_out, int out_size, void* d_ws, size_t ws_size,
                              hipStream_t stream)
{
    const float* X    = (const float*)d_in[0];
    const float* W1   = (const float*)d_in[1];
    const float* b1   = (const float*)d_in[2];
    const float* W2   = (const float*)d_in[3];
    const float* b2   = (const float*)d_in[4];
    const float* W3   = (const float*)d_in[5];
    const float* b3   = (const float*)d_in[6];
    const float* W4   = (const float*)d_in[7];
    const float* b4   = (const float*)d_in[8];
    const float* P0   = (const float*)d_in[9];
    const float* P1   = (const float*)d_in[10];
    const float* P2   = (const float*)d_in[11];
    const float* P3   = (const float*)d_in[12];
    const float* P4   = (const float*)d_in[13];
    const float* P5   = (const float*)d_in[14];
    const float* Ptop = (const float*)d_in[15];
    float* out = (float*)d_out;

    unsigned short* planes = (unsigned short*)d_ws;
    float* base = (float*)d_ws;
    // planes occupy [0, 6124032) floats; fp32 regions start at 6291456
    float* h1c = base + 6291456L;          // [131072][128]
    float* h2c = base + 23068672L;         // [131072][64]
    float* h3c = base + 6291456L;          // [131072][32] (h1c dead)
    float* Fc  = base + 10485760L;         // [131072][32]
    float* t0  = base + 31457280L;         // [64][4096][64]
    float* t1  = base + 6291456L;          // [32][4096][128]
    float* t2  = base + 23068672L;         // [16][4096][256]
    float* t3  = base + 6291456L;          // [8][4096][512]
    float* t4  = base + 39845888L;         // [4][4096][512]
    float* t5  = base + 23068672L;         // [2][4096][512]

    // ---- pre-split weights (frag-ordered planes)
    SegTable T;
    auto seg = [](const float* s, long dst, int Z, int G, int Gpad, int K, int tr, int b0) {
        Seg d; d.src=s; d.dst=dst; d.Z=Z; d.G=G; d.Gpad=Gpad; d.K=K; d.trans=tr; d.blk0=b0; return d;
    };
    T.s[0]  = seg(W1,   0L,        1, 128, 128,  64, 1, 0);
    T.s[1]  = seg(W2,   24576L,    1,  64,  64, 128, 1, 4);
    T.s[2]  = seg(W3,   49152L,    1,  32,  32,  64, 1, 8);
    T.s[3]  = seg(W4,   55296L,    1,  32,  32,  32, 1, 9);
    T.s[4]  = seg(P0,   58368L,   64,  64,  64,  32, 0, 10);
    T.s[5]  = seg(P1,   451584L,  32, 128, 128,  64, 0, 74);
    T.s[6]  = seg(P2,   1238016L, 16, 256, 256, 128, 0, 202);
    T.s[7]  = seg(P3,   2810880L,  8, 512, 512, 256, 0, 458);
    T.s[8]  = seg(P4,   5956608L,  4, 512, 512, 512, 0, 970);
    T.s[9]  = seg(P5,   9102336L,  2, 512, 512, 512, 0, 1482);
    T.s[10] = seg(Ptop, 10675200L, 1, 1000, 1024, 512, 0, 1738);
    presplit<<<dim3(1994), dim3(256), 0, stream>>>(T, planes);

    dim3 blk(256, 1, 1);

    // ---- MLP + leaf, 2 chunks of 131072 tokens
    for (int c = 0; c < 2; ++c) {
        const float* Xc = X + (long)c * 131072 * 64;
        // mlp1: 64->128 relu   (block 128x128, 1024 blocks)
        ht_mfma<2, 2><<<dim3(1024, 1, 1), blk, 0, stream>>>(
            Xc, planes + 0, b1, h1c, 64, 128, 4, 0L, 0L, 64, 0L, 128, 1);
        // mlp2: 128->64 relu   (block 128x64, 1024 blocks)
        ht_mfma<1, 2><<<dim3(1024, 1, 1), blk, 0, stream>>>(
            h1c, planes + 24576, b2, h2c, 128, 64, 2, 0L, 0L, 128, 0L, 64, 1);
        // mlp3: 64->32 relu    (block 256x32, 512 blocks)
        ht_mfma<1, 1><<<dim3(512, 1, 1), blk, 0, stream>>>(
            h2c, planes + 49152, b3, h3c, 64, 32, 1, 0L, 0L, 64, 0L, 32, 1);
        // mlp4: 32->32         (block 256x32, 512 blocks)
        ht_mfma<1, 1><<<dim3(512, 1, 1), blk, 0, stream>>>(
            h3c, planes + 55296, b4, Fc, 32, 32, 1, 0L, 0L, 32, 0L, 32, 0);
        // leaf: t0[j][b][a] = sum_m P0[j][a][m] * F[(b,j)][m]  (1024 blocks)
        ht_mfma<1, 2><<<dim3(16, 1, 64), blk, 0, stream>>>(
            Fc, planes + 58368, nullptr, t0 + (long)c * 131072, 32, 64, 2,
            32L, 0L, 2048, 262144L, 64, 0);
    }

    // ---- tree: t_l[n][b][g] = sum_a P_l[n][g][a] * t[2n][b][a]*t[2n+1][b][a]
    ht_mfma<2, 2><<<dim3(32, 1, 32), blk, 0, stream>>>(   // L1 K=64 G=128 (1024 blk)
        t0, planes + 451584, nullptr, t1, 64, 128, 4,
        524288L, 262144L, 64, 524288L, 128, 0);
    ht_mfma<2, 2><<<dim3(32, 2, 16), blk, 0, stream>>>(   // L2 K=128 G=256 (1024 blk)
        t1, planes + 1238016, nullptr, t2, 128, 256, 8,
        1048576L, 524288L, 128, 1048576L, 256, 0);
    ht_mfma<2, 2><<<dim3(32, 4, 8), blk, 0, stream>>>(    // L3 K=256 G=512 (1024 blk)
        t2, planes + 2810880, nullptr, t3, 256, 512, 16,
        2097152L, 1048576L, 256, 2097152L, 512, 0);
    ht_mfma<2, 2><<<dim3(32, 4, 4), blk, 0, stream>>>(    // L4 K=512 G=512 (512 blk)
        t3, planes + 5956608, nullptr, t4, 512, 512, 16,
        4194304L, 2097152L, 512, 2097152L, 512, 0);
    ht_mfma<1, 2><<<dim3(32, 8, 2), blk, 0, stream>>>(    // L5 K=512 G=512 (512 blk, 128x64)
        t4, planes + 9102336, nullptr, t5, 512, 512, 16,
        4194304L, 2097152L, 512, 2097152L, 512, 0);
    ht_mfma<1, 2><<<dim3(32, 16, 1), blk, 0, stream>>>(   // top K=512 G=1000 pad1024 (512 blk)
        t5, planes + 10675200, nullptr, out, 512, 1000, 32,
        0L, 2097152L, 512, 0L, 1000, 0);
}